// Round 2
// baseline (150.002 us; speedup 1.0000x reference)
//
#include <hip/hip_runtime.h>
#include <math.h>

#define H_  128
#define N_  64
#define L_  4096
#define B_  8
#define LC  128       // chunk length
#define LCP (LC + 4)  // padded chunk row (floats) -> chunk k base bank = 4k
#define NCH 32        // number of chunks (L_/LC)
#define TPB 256
#define MPL 8         // modes per lane

// One block per (b,h). Chunked parallel scan over L with N=64 complex modes.
// y[l] = Re(sum_n c_n * x_n[l]) + D*u[l],  x_n[l] = r_n x_n[l-1] + u[l]
// r = exp(step*Lambda);  c = (W/Lambda)*conj(s)/(|s|^2+EPS);  s = (1-r^L)/(1-r)
__global__ __launch_bounds__(TPB, 4)
void dss_fwd(const float* __restrict__ u,
             const float* __restrict__ Lre,
             const float* __restrict__ Lim,
             const float* __restrict__ Wri,
             const float* __restrict__ Dv,
             const float* __restrict__ lstep,
             float* __restrict__ out)
{
    __shared__ float su[NCH * LCP];          // staged u, padded rows (16.5 KB)
    __shared__ float sE[NCH * LCP];          // end-states/carries, then y (16.5 KB)
    __shared__ float s_rre[N_], s_rim[N_];   // r
    __shared__ float s_cre[N_], s_cim[N_];   // c
    __shared__ float s_qre[N_], s_qim[N_];   // r^LC

    const int t  = threadIdx.x;
    const int bh = blockIdx.x;               // b*H + h
    const int h  = bh % H_;

    // stage u (coalesced float4 in, padded rows in LDS)
    {
        const float4* up = reinterpret_cast<const float4*>(u + (size_t)bh * L_);
        #pragma unroll
        for (int i = 0; i < L_/4/TPB; ++i) {
            const int e4 = t + i*TPB;        // float4 slot
            const int ch = e4 >> 5;          // 32 float4 per chunk
            const int o4 = e4 & 31;
            *reinterpret_cast<float4*>(&su[ch*LCP + o4*4]) = up[e4];
        }
    }

    // per-(h,n) constants in double (one-time, wave 0)
    if (t < N_) {
        const int n = t;
        const float stepf = expf(lstep[h]);          // matches jnp.exp in f32
        const float a  = stepf * Lre[h*N_ + n];      // f32 to match P construction
        const float bp = stepf * Lim[h*N_ + n];
        const double ad = (double)a, bd = (double)bp;
        const double em = exp(ad);
        const double rre = em * cos(bd), rim = em * sin(bd);
        const double eL = exp(ad * (double)L_);
        const double rLre = eL * cos(bd * (double)L_), rLim = eL * sin(bd * (double)L_);
        // s = (1 - r^L) / (1 - r)
        const double nre = 1.0 - rLre, nim = -rLim;
        const double dre = 1.0 - rre,  dim = -rim;
        const double dm  = dre*dre + dim*dim;
        const double sre = (nre*dre + nim*dim) / dm;
        const double sim = (nim*dre - nre*dim) / dm;
        // W / Lambda
        const double wre = (double)Wri[(h*N_ + n)*2 + 0];
        const double wim = (double)Wri[(h*N_ + n)*2 + 1];
        const double lre = (double)Lre[h*N_ + n], lim = (double)Lim[h*N_ + n];
        const double lm  = lre*lre + lim*lim;
        const double wor = (wre*lre + wim*lim) / lm;
        const double woi = (wim*lre - wre*lim) / lm;
        // c = (W/Lambda) * conj(s) / (|s|^2 + EPS)
        const double sm  = sre*sre + sim*sim + 1e-7;
        const double cre = (wor*sre + woi*sim) / sm;
        const double cim = (woi*sre - wor*sim) / sm;
        // q = r^LC
        const double eC = exp(ad * (double)LC);
        s_rre[n] = (float)rre;  s_rim[n] = (float)rim;
        s_cre[n] = (float)cre;  s_cim[n] = (float)cim;
        s_qre[n] = (float)(eC * cos(bd * (double)LC));
        s_qim[n] = (float)(eC * sin(bd * (double)LC));
    }
    __syncthreads();

    const int k = t >> 3;       // chunk owned by this lane's 8-lane group
    const int g = t & 7;        // lane within group (8 modes each)
    const int base = k * LCP;

    float rre[MPL], rim[MPL], ccr[MPL], cci[MPL];
    #pragma unroll
    for (int m = 0; m < MPL; ++m) {
        const int n = g*MPL + m;
        rre[m] = s_rre[n]; rim[m] = s_rim[n];
        ccr[m] = s_cre[n]; cci[m] = s_cim[n];
    }
    const float Dh = Dv[h];

    float xr[MPL], xi[MPL];
    #pragma unroll
    for (int m = 0; m < MPL; ++m) { xr[m] = 0.f; xi[m] = 0.f; }

#define MODE_STEP(uv)                                                     \
    _Pragma("unroll")                                                     \
    for (int m = 0; m < MPL; ++m) {                                       \
        const float nr = fmaf(rre[m], xr[m], fmaf(-rim[m], xi[m], (uv))); \
        const float ni = fmaf(rre[m], xi[m], rim[m]*xr[m]);               \
        xr[m] = nr; xi[m] = ni;                                           \
    }

    // ---- phase 1: local end-state of each chunk (zero carry-in) ----
    #pragma unroll 2
    for (int j = 0; j < LC; j += 4) {
        const float4 u4 = *reinterpret_cast<const float4*>(&su[base + j]);
        MODE_STEP(u4.x); MODE_STEP(u4.y); MODE_STEP(u4.z); MODE_STEP(u4.w);
    }
    #pragma unroll
    for (int m = 0; m < MPL; m += 2) {
        const float4 v = make_float4(xr[m], xi[m], xr[m+1], xi[m+1]);
        *reinterpret_cast<float4*>(&sE[(k*N_ + g*MPL + m)*2]) = v;
    }
    __syncthreads();

    // ---- phase 2: carry scan over chunks (wave 0, one mode per lane) ----
    // Bulk-preload all end-states (independent ds_reads), then pure-FMA chain.
    // in-place: E[k][n] <- carry_k, carry_{k+1} = q*carry_k + E_k
    if (t < N_) {
        const int n = t;
        float2 E[NCH];
        #pragma unroll
        for (int kk = 0; kk < NCH; ++kk)
            E[kk] = *reinterpret_cast<const float2*>(&sE[(kk*N_ + n)*2]);
        const float qre = s_qre[n], qim = s_qim[n];
        float cr = 0.f, ci = 0.f;
        #pragma unroll
        for (int kk = 0; kk < NCH; ++kk) {
            *reinterpret_cast<float2*>(&sE[(kk*N_ + n)*2]) = make_float2(cr, ci);
            const float ncr = fmaf(qre, cr, fmaf(-qim, ci, E[kk].x));
            const float nci = fmaf(qre, ci, fmaf(qim, cr, E[kk].y));
            cr = ncr; ci = nci;
        }
    }
    __syncthreads();

    // ---- load carry-in for this chunk ----
    #pragma unroll
    for (int m = 0; m < MPL; m += 2) {
        const float4 v = *reinterpret_cast<const float4*>(&sE[(k*N_ + g*MPL + m)*2]);
        xr[m] = v.x; xi[m] = v.y; xr[m+1] = v.z; xi[m+1] = v.w;
    }
    __syncthreads();   // all carries in regs before sE is overwritten with y

    // ---- phase 3: recompute with carry-in, emit y into padded sE ----
    #pragma unroll 2
    for (int j = 0; j < LC; j += 4) {
        const float4 u4 = *reinterpret_cast<const float4*>(&su[base + j]);
        float a0, a1, a2, a3;
#define MODE_STEP_ACC(uv, acc)                                            \
        {                                                                 \
            float accA = 0.f, accB = 0.f;                                 \
            _Pragma("unroll")                                             \
            for (int m = 0; m < MPL; ++m) {                               \
                const float nr = fmaf(rre[m], xr[m], fmaf(-rim[m], xi[m], (uv))); \
                const float ni = fmaf(rre[m], xi[m], rim[m]*xr[m]);       \
                xr[m] = nr; xi[m] = ni;                                   \
                if (m < MPL/2) {                                          \
                    accA = fmaf(ccr[m],  nr, accA);                       \
                    accA = fmaf(-cci[m], ni, accA);                       \
                } else {                                                  \
                    accB = fmaf(ccr[m],  nr, accB);                       \
                    accB = fmaf(-cci[m], ni, accB);                       \
                }                                                         \
            }                                                             \
            (acc) = accA + accB;                                          \
        }
        MODE_STEP_ACC(u4.x, a0);
        MODE_STEP_ACC(u4.y, a1);
        MODE_STEP_ACC(u4.z, a2);
        MODE_STEP_ACC(u4.w, a3);
        // 4 independent 3-level reduction chains (latency overlaps)
        a0 += __shfl_xor(a0, 1); a1 += __shfl_xor(a1, 1);
        a2 += __shfl_xor(a2, 1); a3 += __shfl_xor(a3, 1);
        a0 += __shfl_xor(a0, 2); a1 += __shfl_xor(a1, 2);
        a2 += __shfl_xor(a2, 2); a3 += __shfl_xor(a3, 2);
        a0 += __shfl_xor(a0, 4); a1 += __shfl_xor(a1, 4);
        a2 += __shfl_xor(a2, 4); a3 += __shfl_xor(a3, 4);
        if (g == 0) {
            const float4 y4 = make_float4(fmaf(Dh, u4.x, a0), fmaf(Dh, u4.y, a1),
                                          fmaf(Dh, u4.z, a2), fmaf(Dh, u4.w, a3));
            *reinterpret_cast<float4*>(&sE[base + j]) = y4;
        }
    }
    __syncthreads();

    // ---- flush: pure copy, coalesced ----
    {
        float4* op = reinterpret_cast<float4*>(out + (size_t)bh * L_);
        #pragma unroll
        for (int i = 0; i < L_/4/TPB; ++i) {
            const int e4 = t + i*TPB;
            const int ch = e4 >> 5;
            const int o4 = e4 & 31;
            op[e4] = *reinterpret_cast<const float4*>(&sE[ch*LCP + o4*4]);
        }
    }
}

extern "C" void kernel_launch(void* const* d_in, const int* in_sizes, int n_in,
                              void* d_out, int out_size, void* d_ws, size_t ws_size,
                              hipStream_t stream) {
    const float* u  = (const float*)d_in[0];
    const float* lr = (const float*)d_in[1];
    const float* li = (const float*)d_in[2];
    const float* w  = (const float*)d_in[3];
    const float* dv = (const float*)d_in[4];
    const float* ls = (const float*)d_in[5];
    float* out = (float*)d_out;
    dss_fwd<<<dim3(B_*H_), dim3(TPB), 0, stream>>>(u, lr, li, w, dv, ls, out);
}

// Round 3
// 105.315 us; speedup vs baseline: 1.4243x; 1.4243x over previous
//
#include <hip/hip_runtime.h>
#include <math.h>

#define H_  128
#define N_  64
#define L_  4096
#define B_  8
#define LC  128
#define NCH 32     // L_/LC

typedef _Float16 f16;
typedef _Float16 half8 __attribute__((ext_vector_type(8)));
typedef _Float16 f16x4 __attribute__((ext_vector_type(4)));
typedef _Float16 f16x2 __attribute__((ext_vector_type(2)));
typedef float    floatx4 __attribute__((ext_vector_type(4)));

// ws layout (bytes): T | G | M (each H_*LC*LC f16) | q (H_*N_*2 f32)
#define WS_T 0
#define WS_G ((size_t)H_*LC*LC*2)
#define WS_M ((size_t)2*H_*LC*LC*2)
#define WS_Q ((size_t)3*H_*LC*LC*2)
// total = 12 MB + 64 KB

// ---------------- K1: per-h constants + T/G/M/q build ----------------
// T[i*128+j] = (i>=j) ? K'[i-j] : 0      (K'[0] = K[0]+D; B-matrix stored [n=i][k=j])
// G[(2m)*128+k]   = Re(r_m^{127-k}),  G[(2m+1)*128+k] = Im(r_m^{127-k})
// M[j*128+2m]     = 16*Re(c_m r_m^{j+1}), M[j*128+2m+1] = -16*Im(c_m r_m^{j+1})
__global__ __launch_bounds__(256)
void dss_prep(const float* __restrict__ Lre, const float* __restrict__ Lim,
              const float* __restrict__ Wri, const float* __restrict__ Dv,
              const float* __restrict__ lstep, char* __restrict__ ws)
{
    __shared__ float s_rre[N_], s_rim[N_], s_cre[N_], s_cim[N_];
    __shared__ float sRT[N_][130];   // Re(c * r^t), padded
    __shared__ float sK[LC];
    const int h = blockIdx.x;
    const int t = threadIdx.x;
    f16*   Tg = (f16*)(ws + WS_T) + (size_t)h*LC*LC;
    f16*   Gg = (f16*)(ws + WS_G) + (size_t)h*LC*LC;
    f16*   Mg = (f16*)(ws + WS_M) + (size_t)h*LC*LC;
    float* qg = (float*)(ws + WS_Q) + (size_t)h*N_*2;

    if (t < N_) {
        const int n = t;
        const float stepf = expf(lstep[h]);
        const float a  = stepf * Lre[h*N_ + n];
        const float bp = stepf * Lim[h*N_ + n];
        const double ad = (double)a, bd = (double)bp;
        const double em = exp(ad);
        const double rre = em * cos(bd), rim = em * sin(bd);
        const double eL = exp(ad * (double)L_);
        const double rLre = eL * cos(bd * (double)L_), rLim = eL * sin(bd * (double)L_);
        const double nre = 1.0 - rLre, nim = -rLim;
        const double dre = 1.0 - rre,  dim = -rim;
        const double dm  = dre*dre + dim*dim;
        const double sre = (nre*dre + nim*dim) / dm;
        const double sim = (nim*dre - nre*dim) / dm;
        const double wre = (double)Wri[(h*N_ + n)*2 + 0];
        const double wim = (double)Wri[(h*N_ + n)*2 + 1];
        const double lre = (double)Lre[h*N_ + n], lim = (double)Lim[h*N_ + n];
        const double lm  = lre*lre + lim*lim;
        const double wor = (wre*lre + wim*lim) / lm;
        const double woi = (wim*lre - wre*lim) / lm;
        const double sm  = sre*sre + sim*sim + 1e-7;
        const double cre = (wor*sre + woi*sim) / sm;
        const double cim = (woi*sre - wor*sim) / sm;
        const double eC = exp(ad * (double)LC);
        s_rre[n] = (float)rre;  s_rim[n] = (float)rim;
        s_cre[n] = (float)cre;  s_cim[n] = (float)cim;
        qg[2*n]   = (float)(eC * cos(bd * (double)LC));
        qg[2*n+1] = (float)(eC * sin(bd * (double)LC));
    }
    __syncthreads();

    // per-mode geometric sequence Re(c r^t)
    if (t < N_) {
        const float rr = s_rre[t], ri = s_rim[t];
        float wr = s_cre[t], wi = s_cim[t];
        for (int j = 0; j < LC; ++j) {
            sRT[t][j] = wr;
            const float nr2 = wr*rr - wi*ri, ni2 = wr*ri + wi*rr;
            wr = nr2; wi = ni2;
        }
    }
    __syncthreads();
    if (t < LC) {
        float acc = 0.f;
        for (int n = 0; n < N_; ++n) acc += sRT[n][t];
        if (t == 0) acc += Dv[h];          // fold D*u into local Toeplitz diag
        sK[t] = acc;
    }
    __syncthreads();
    // T fill (all 256 threads)
    for (int e = t; e < LC*LC; e += 256) {
        const int i = e >> 7, j = e & 127;
        Tg[e] = (f16)((i >= j) ? sK[i-j] : 0.f);
    }
    // G and M fills (wave 0, per-mode recurrences, f32)
    if (t < N_) {
        const float rr = s_rre[t], ri = s_rim[t];
        {   // G: w = r^{127-k}, iterate k downward starting w=1 at k=127
            float wr = 1.f, wi = 0.f;
            for (int k = LC-1; k >= 0; --k) {
                Gg[(2*t)*LC + k]   = (f16)wr;
                Gg[(2*t+1)*LC + k] = (f16)wi;
                const float nr2 = wr*rr - wi*ri, ni2 = wr*ri + wi*rr;
                wr = nr2; wi = ni2;
            }
        }
        {   // M: w = 16*c*r^{j+1}
            float mr = (s_cre[t]*rr - s_cim[t]*ri) * 16.f;
            float mi = (s_cre[t]*ri + s_cim[t]*rr) * 16.f;
            for (int j = 0; j < LC; ++j) {
                Mg[j*LC + 2*t]   = (f16)mr;
                Mg[j*LC + 2*t+1] = (f16)(-mi);
                const float nr2 = mr*rr - mi*ri, ni2 = mr*ri + mi*rr;
                mr = nr2; mi = ni2;
            }
        }
    }
}

// ---------------- K2: main — 3 batched GEMMs + carry scan ----------------
__global__ __launch_bounds__(256, 4)
void dss_main(const float* __restrict__ u, const char* __restrict__ ws,
              float* __restrict__ out)
{
    __shared__ f16   sU[NCH][132];    // u chunks, f16, padded rows
    __shared__ float sE[NCH][130];    // end-states f32
    __shared__ f16   sC[NCH][132];    // carries (f16, scaled 1/16)

    const int t  = threadIdx.x;
    const int bh = blockIdx.x;
    const int h  = bh & (H_-1);
    const f16* Tg = (const f16*)(ws + WS_T) + (size_t)h*LC*LC;
    const f16* Gg = (const f16*)(ws + WS_G) + (size_t)h*LC*LC;
    const f16* Mg = (const f16*)(ws + WS_M) + (size_t)h*LC*LC;
    const float* qg = (const float*)(ws + WS_Q) + (size_t)h*N_*2;

    // stage u -> f16 LDS
    {
        const float4* up = reinterpret_cast<const float4*>(u + (size_t)bh * L_);
        #pragma unroll
        for (int i = 0; i < L_/4/256; ++i) {
            const int e4 = t + i*256;
            const float4 v = up[e4];
            const int row = e4 >> 5, c4 = (e4 & 31) * 4;
            f16x4 pv = { (f16)v.x, (f16)v.y, (f16)v.z, (f16)v.w };
            *reinterpret_cast<f16x4*>(&sU[row][c4]) = pv;
        }
    }
    __syncthreads();

    const int w  = t >> 6;     // wave 0..3 -> n-tiles {2w, 2w+1}
    const int l  = t & 63;
    const int lr = l & 15;     // tile row/col index
    const int lg = l >> 4;     // k-group / output-row group

    floatx4 accA[2][2] = {};   // [mtile][nt] — y accumulators (phases A + C)
    floatx4 accB[2][2] = {};   // end-state accumulators (phase B)

    // phases A (Y_loc = U*T) and B (E = U*G), fused over the K loop
    #pragma unroll
    for (int ks = 0; ks < 4; ++ks) {
        const int ko = ks*32 + lg*8;
        const half8 a0 = *reinterpret_cast<const half8*>(&sU[lr     ][ko]);
        const half8 a1 = *reinterpret_cast<const half8*>(&sU[16 + lr][ko]);
        #pragma unroll
        for (int nt = 0; nt < 2; ++nt) {
            const int ncol = (2*w + nt)*16 + lr;
            const half8 bT = *reinterpret_cast<const half8*>(&Tg[ncol*LC + ko]);
            const half8 bG = *reinterpret_cast<const half8*>(&Gg[ncol*LC + ko]);
            accA[0][nt] = __builtin_amdgcn_mfma_f32_16x16x32_f16(a0, bT, accA[0][nt], 0, 0, 0);
            accA[1][nt] = __builtin_amdgcn_mfma_f32_16x16x32_f16(a1, bT, accA[1][nt], 0, 0, 0);
            accB[0][nt] = __builtin_amdgcn_mfma_f32_16x16x32_f16(a0, bG, accB[0][nt], 0, 0, 0);
            accB[1][nt] = __builtin_amdgcn_mfma_f32_16x16x32_f16(a1, bG, accB[1][nt], 0, 0, 0);
        }
    }
    // spill E fragments to LDS
    #pragma unroll
    for (int mt = 0; mt < 2; ++mt)
        #pragma unroll
        for (int nt = 0; nt < 2; ++nt)
            #pragma unroll
            for (int j = 0; j < 4; ++j)
                sE[mt*16 + lg*4 + j][(2*w + nt)*16 + lr] = accB[mt][nt][j];
    __syncthreads();

    // carry scan (wave 0; lane = mode). carry_0 = 0; carry_{k+1} = q*carry_k + E_k
    if (w == 0) {
        const float qre = qg[2*l], qim = qg[2*l+1];
        float cr = 0.f, ci = 0.f;
        #pragma unroll
        for (int k = 0; k < NCH; ++k) {
            const float er = sE[k][2*l], ei = sE[k][2*l+1];
            *reinterpret_cast<f16x2*>(&sC[k][2*l]) =
                (f16x2){ (f16)(cr * 0.0625f), (f16)(ci * 0.0625f) };
            const float ncr = fmaf(qre, cr, fmaf(-qim, ci, er));
            const float nci = fmaf(qre, ci, fmaf( qim, cr, ei));
            cr = ncr; ci = nci;
        }
    }
    __syncthreads();

    // phase C: Y += C * M (chained into accA)
    #pragma unroll
    for (int ks = 0; ks < 4; ++ks) {
        const int ko = ks*32 + lg*8;
        const half8 a0 = *reinterpret_cast<const half8*>(&sC[lr     ][ko]);
        const half8 a1 = *reinterpret_cast<const half8*>(&sC[16 + lr][ko]);
        #pragma unroll
        for (int nt = 0; nt < 2; ++nt) {
            const int ncol = (2*w + nt)*16 + lr;
            const half8 bM = *reinterpret_cast<const half8*>(&Mg[ncol*LC + ko]);
            accA[0][nt] = __builtin_amdgcn_mfma_f32_16x16x32_f16(a0, bM, accA[0][nt], 0, 0, 0);
            accA[1][nt] = __builtin_amdgcn_mfma_f32_16x16x32_f16(a1, bM, accA[1][nt], 0, 0, 0);
        }
    }

    // epilogue: C/D layout col=lane&15, row=4*(lane>>4)+j
    float* op = out + (size_t)bh * L_;
    #pragma unroll
    for (int mt = 0; mt < 2; ++mt)
        #pragma unroll
        for (int nt = 0; nt < 2; ++nt) {
            const int pos = (2*w + nt)*16 + lr;
            #pragma unroll
            for (int j = 0; j < 4; ++j) {
                const int chunk = mt*16 + lg*4 + j;
                op[chunk*LC + pos] = accA[mt][nt][j];
            }
        }
}

extern "C" void kernel_launch(void* const* d_in, const int* in_sizes, int n_in,
                              void* d_out, int out_size, void* d_ws, size_t ws_size,
                              hipStream_t stream) {
    const float* u  = (const float*)d_in[0];
    const float* lr = (const float*)d_in[1];
    const float* li = (const float*)d_in[2];
    const float* w  = (const float*)d_in[3];
    const float* dv = (const float*)d_in[4];
    const float* ls = (const float*)d_in[5];
    float* out = (float*)d_out;
    char* ws = (char*)d_ws;
    dss_prep<<<dim3(H_), dim3(256), 0, stream>>>(lr, li, w, dv, ls, ws);
    dss_main<<<dim3(B_*H_), dim3(256), 0, stream>>>(u, ws, out);
}